// Round 1
// baseline (2205.926 us; speedup 1.0000x reference)
//
#include <hip/hip_runtime.h>

// HeteroSAGE on MI355X — round 1: correctness-first fp32.
// Structure exploited: e_tx_c / e_tx_m are arange(E), E == N_TX, so every tx
// has exactly one card edge and one merch edge (cnt==1). The tx-side SAGE mean
// becomes a row gather of p_card = h_card @ Wl0 (matmul BEFORE gather).
// Card/merch aggregation is a general scatter-mean via fp32 atomics.

#define N_TX    200000
#define N_CARD  50000
#define N_MERCH 10000
#define NE      200000
#define TM 64
#define KC 32

// Unified fp32 GEMM: OUT[M,128] = act( meanA1 @ W1 (+ A2 @ W2) + bias
//                                      + P1[I1[r]] + P2[I2[r]] )
// optional final head: out[r] = relu(row) . h2W + h2b
__global__ __launch_bounds__(256) void fused_gemm(
    const float* __restrict__ A1, const int* __restrict__ rowIdx1,
    const float* __restrict__ cnt1, int K1,
    const float* __restrict__ W1,
    const float* __restrict__ A2, const float* __restrict__ W2, int K2,
    const float* __restrict__ bias,
    const float* __restrict__ P1, const int* __restrict__ I1,
    const float* __restrict__ P2, const int* __restrict__ I2,
    int do_relu,
    const float* __restrict__ h2W, const float* __restrict__ h2b,
    float* __restrict__ OUT,
    int M)
{
    __shared__ float At[KC][TM + 4];   // transposed A tile: [k][row], pad +4
    __shared__ float Wt[KC][128];
    const int tid = threadIdx.x;
    const int tc = tid & 31;           // col group: cols tc*4 .. tc*4+3
    const int tr = tid >> 5;           // row group: rows tr*8 .. tr*8+7
    const int base = blockIdx.x * TM;

    float acc[8][4];
#pragma unroll
    for (int i = 0; i < 8; ++i)
#pragma unroll
        for (int j = 0; j < 4; ++j) acc[i][j] = 0.f;

    for (int pair = 0; pair < 2; ++pair) {
        const float* A = (pair == 0) ? A1 : A2;
        if (!A) continue;
        const float* W = (pair == 0) ? W1 : W2;
        const int K = (pair == 0) ? K1 : K2;
        const int* rIdx = (pair == 0) ? rowIdx1 : nullptr;
        const float* cnt = (pair == 0) ? cnt1 : nullptr;
        const int nkc = K >> 5;
        for (int kc = 0; kc < nkc; ++kc) {
            const int k0 = kc << 5;
            __syncthreads();
            // stage A tile (64 rows x 32 k) transposed into LDS
#pragma unroll
            for (int t = 0; t < 2; ++t) {
                int u = tid * 2 + t;           // 0..511
                int r = u >> 3;                // 0..63
                int q = u & 7;                 // which float4 of the 32-k chunk
                int gr = base + r;
                float4 v = make_float4(0.f, 0.f, 0.f, 0.f);
                if (gr < M) {
                    int ar = rIdx ? rIdx[gr] : gr;
                    v = *reinterpret_cast<const float4*>(A + (size_t)ar * K + k0 + q * 4);
                    if (cnt) {
                        float inv = 1.0f / fmaxf(cnt[gr], 1.0f);
                        v.x *= inv; v.y *= inv; v.z *= inv; v.w *= inv;
                    }
                }
                At[q * 4 + 0][r] = v.x; At[q * 4 + 1][r] = v.y;
                At[q * 4 + 2][r] = v.z; At[q * 4 + 3][r] = v.w;
            }
            // stage W tile (32 k x 128 cols)
#pragma unroll
            for (int t = 0; t < 4; ++t) {
                int u = tid + t * 256;         // 0..1023
                int k = u >> 5;
                int c4 = u & 31;
                *reinterpret_cast<float4*>(&Wt[k][c4 * 4]) =
                    *reinterpret_cast<const float4*>(W + (size_t)(k0 + k) * 128 + c4 * 4);
            }
            __syncthreads();
#pragma unroll
            for (int k = 0; k < KC; ++k) {
                float4 bq = *reinterpret_cast<const float4*>(&Wt[k][tc * 4]);
                float4 a0 = *reinterpret_cast<const float4*>(&At[k][tr * 8]);
                float4 a1 = *reinterpret_cast<const float4*>(&At[k][tr * 8 + 4]);
                float av[8] = {a0.x, a0.y, a0.z, a0.w, a1.x, a1.y, a1.z, a1.w};
                float bv[4] = {bq.x, bq.y, bq.z, bq.w};
#pragma unroll
                for (int i = 0; i < 8; ++i)
#pragma unroll
                    for (int j = 0; j < 4; ++j)
                        acc[i][j] = fmaf(av[i], bv[j], acc[i][j]);
            }
        }
    }

    // epilogue
    float4 bi = make_float4(0.f, 0.f, 0.f, 0.f);
    if (bias) bi = *reinterpret_cast<const float4*>(bias + tc * 4);
    float4 h2v = make_float4(0.f, 0.f, 0.f, 0.f);
    if (h2W) h2v = *reinterpret_cast<const float4*>(h2W + tc * 4);

#pragma unroll
    for (int i = 0; i < 8; ++i) {
        int gr = base + tr * 8 + i;
        bool valid = gr < M;
        int grc = valid ? gr : 0;
        float4 o;
        o.x = acc[i][0] + bi.x; o.y = acc[i][1] + bi.y;
        o.z = acc[i][2] + bi.z; o.w = acc[i][3] + bi.w;
        if (P1) {
            int ix = I1 ? I1[grc] : grc;
            float4 p = *reinterpret_cast<const float4*>(P1 + (size_t)ix * 128 + tc * 4);
            o.x += p.x; o.y += p.y; o.z += p.z; o.w += p.w;
        }
        if (P2) {
            int ix = I2 ? I2[grc] : grc;
            float4 p = *reinterpret_cast<const float4*>(P2 + (size_t)ix * 128 + tc * 4);
            o.x += p.x; o.y += p.y; o.z += p.z; o.w += p.w;
        }
        if (do_relu) {
            o.x = fmaxf(o.x, 0.f); o.y = fmaxf(o.y, 0.f);
            o.z = fmaxf(o.z, 0.f); o.w = fmaxf(o.w, 0.f);
        }
        if (h2W) {
            float s = o.x * h2v.x + o.y * h2v.y + o.z * h2v.z + o.w * h2v.w;
            s += __shfl_xor(s, 1);  s += __shfl_xor(s, 2);
            s += __shfl_xor(s, 4);  s += __shfl_xor(s, 8);
            s += __shfl_xor(s, 16);            // reduce across the 32 col-lanes
            if (tc == 0 && valid) OUT[gr] = s + h2b[0];
        } else if (valid) {
            *reinterpret_cast<float4*>(OUT + (size_t)gr * 128 + tc * 4) = o;
        }
    }
}

// scatter h_tx rows into card/merch accumulators (+counts). 32 threads/edge.
__global__ __launch_bounds__(256) void scatter_agg(
    const float* __restrict__ h_tx,
    const int* __restrict__ e_card, const int* __restrict__ e_tx_c,
    const int* __restrict__ e_merch, const int* __restrict__ e_tx_m,
    float* __restrict__ agg_card, float* __restrict__ cnt_card,
    float* __restrict__ agg_merch, float* __restrict__ cnt_merch, int E)
{
    int sub = threadIdx.x & 31;
    int e = blockIdx.x * 8 + (threadIdx.x >> 5);
    if (e >= E) return;
    int tsc = e_tx_c[e];
    int c   = e_card[e];
    int tsm = e_tx_m[e];
    int m   = e_merch[e];
    float4 v = *reinterpret_cast<const float4*>(h_tx + (size_t)tsc * 128 + sub * 4);
    atomicAdd(&agg_card[(size_t)c * 128 + sub * 4 + 0], v.x);
    atomicAdd(&agg_card[(size_t)c * 128 + sub * 4 + 1], v.y);
    atomicAdd(&agg_card[(size_t)c * 128 + sub * 4 + 2], v.z);
    atomicAdd(&agg_card[(size_t)c * 128 + sub * 4 + 3], v.w);
    float4 v2 = (tsm == tsc) ? v
        : *reinterpret_cast<const float4*>(h_tx + (size_t)tsm * 128 + sub * 4);
    atomicAdd(&agg_merch[(size_t)m * 128 + sub * 4 + 0], v2.x);
    atomicAdd(&agg_merch[(size_t)m * 128 + sub * 4 + 1], v2.y);
    atomicAdd(&agg_merch[(size_t)m * 128 + sub * 4 + 2], v2.z);
    atomicAdd(&agg_merch[(size_t)m * 128 + sub * 4 + 3], v2.w);
    if (sub == 0) {
        atomicAdd(&cnt_card[c], 1.0f);
        atomicAdd(&cnt_merch[m], 1.0f);
    }
}

// Wsum = Wr0 + Wr2, bsum = bl0 + bl2 (tx dst gets sum over two edge types)
__global__ void wsum_kernel(const float* __restrict__ w0, const float* __restrict__ w2,
                            const float* __restrict__ b0, const float* __restrict__ b2,
                            float* __restrict__ Wsum, float* __restrict__ bsum)
{
    int i = blockIdx.x * 256 + threadIdx.x;
    if (i < 16384) Wsum[i] = w0[i] + w2[i];
    if (i < 128) bsum[i] = b0[i] + b2[i];
}

extern "C" void kernel_launch(void* const* d_in, const int* in_sizes, int n_in,
                              void* d_out, int out_size, void* d_ws, size_t ws_size,
                              hipStream_t stream)
{
    const float* tx_x        = (const float*)d_in[0];
    const int*   card_ids    = (const int*)d_in[1];
    const int*   merch_ids   = (const int*)d_in[2];
    const int*   e_card      = (const int*)d_in[3];
    const int*   e_tx_c      = (const int*)d_in[4];
    const int*   e_merch     = (const int*)d_in[5];
    const int*   e_tx_m      = (const int*)d_in[6];
    const float* card_emb    = (const float*)d_in[7];
    const float* merch_emb   = (const float*)d_in[8];
    const float* card_proj_W = (const float*)d_in[9];
    const float* card_proj_b = (const float*)d_in[10];
    const float* merch_proj_W= (const float*)d_in[11];
    const float* merch_proj_b= (const float*)d_in[12];
    const float* tx_W        = (const float*)d_in[13];
    const float* tx_b        = (const float*)d_in[14];
    const float* conv_Wl     = (const float*)d_in[15];
    const float* conv_bl     = (const float*)d_in[16];
    const float* conv_Wr     = (const float*)d_in[17];
    const float* h1_W        = (const float*)d_in[18];
    const float* h1_b        = (const float*)d_in[19];
    const float* h2_W        = (const float*)d_in[20];
    const float* h2_b        = (const float*)d_in[21];

    float* ws = (float*)d_ws;
    float* h_tx    = ws; ws += (size_t)N_TX * 128;      // 25.6M
    float* h_card  = ws; ws += (size_t)N_CARD * 128;    //  6.4M
    float* h_merch = ws; ws += (size_t)N_MERCH * 128;   //  1.28M
    float* p_card  = ws; ws += (size_t)N_CARD * 128;
    float* p_merch = ws; ws += (size_t)N_MERCH * 128;
    float* agg_card  = ws; ws += (size_t)N_CARD * 128;  // contiguous zero region:
    float* agg_merch = ws; ws += (size_t)N_MERCH * 128; // agg_card..cnt_merch
    float* cnt_card  = ws; ws += N_CARD;
    float* cnt_merch = ws; ws += N_MERCH;
    float* Wsum = ws; ws += 128 * 128;
    float* bsum = ws; ws += 128;
    const size_t zero_bytes =
        ((size_t)N_CARD * 128 + (size_t)N_MERCH * 128 + N_CARD + N_MERCH) * 4;

    auto gemm = [&](const float* A1, const int* ri, const float* cnt, int K1,
                    const float* W1, const float* A2, const float* W2, int K2,
                    const float* bias, const float* P1, const int* I1,
                    const float* P2, const int* I2, int relu,
                    const float* h2w, const float* h2bb, float* out, int M) {
        fused_gemm<<<dim3((M + TM - 1) / TM), dim3(256), 0, stream>>>(
            A1, ri, cnt, K1, W1, A2, W2, K2, bias, P1, I1, P2, I2, relu,
            h2w, h2bb, out, M);
    };

    // input encoders
    gemm(tx_x, nullptr, nullptr, 128, tx_W, nullptr, nullptr, 0, tx_b,
         nullptr, nullptr, nullptr, nullptr, 1, nullptr, nullptr, h_tx, N_TX);
    gemm(card_emb, card_ids, nullptr, 64, card_proj_W, nullptr, nullptr, 0,
         card_proj_b, nullptr, nullptr, nullptr, nullptr, 0, nullptr, nullptr,
         h_card, N_CARD);
    gemm(merch_emb, merch_ids, nullptr, 64, merch_proj_W, nullptr, nullptr, 0,
         merch_proj_b, nullptr, nullptr, nullptr, nullptr, 0, nullptr, nullptr,
         h_merch, N_MERCH);

    for (int l = 0; l < 2; ++l) {
        const float* Wl = conv_Wl + (size_t)l * 4 * 16384;
        const float* Wr = conv_Wr + (size_t)l * 4 * 16384;
        const float* bl = conv_bl + (size_t)l * 4 * 128;

        hipMemsetAsync(agg_card, 0, zero_bytes, stream);
        scatter_agg<<<dim3((NE + 7) / 8), dim3(256), 0, stream>>>(
            h_tx, e_card, e_tx_c, e_merch, e_tx_m,
            agg_card, cnt_card, agg_merch, cnt_merch, NE);
        wsum_kernel<<<dim3(64), dim3(256), 0, stream>>>(
            Wr + 0 * 16384, Wr + 2 * 16384, bl + 0 * 128, bl + 2 * 128, Wsum, bsum);

        // p_* = h_* @ Wl[etype] (pre-update hidden, projected) for the tx gather
        gemm(h_card, nullptr, nullptr, 128, Wl + 0 * 16384, nullptr, nullptr, 0,
             nullptr, nullptr, nullptr, nullptr, nullptr, 0, nullptr, nullptr,
             p_card, N_CARD);
        gemm(h_merch, nullptr, nullptr, 128, Wl + 2 * 16384, nullptr, nullptr, 0,
             nullptr, nullptr, nullptr, nullptr, nullptr, 0, nullptr, nullptr,
             p_merch, N_MERCH);

        // card/merch updates: relu(mean @ Wl + h @ Wr + bl), in-place (row-local)
        gemm(agg_card, nullptr, cnt_card, 128, Wl + 1 * 16384,
             h_card, Wr + 1 * 16384, 128, bl + 1 * 128,
             nullptr, nullptr, nullptr, nullptr, 1, nullptr, nullptr, h_card, N_CARD);
        gemm(agg_merch, nullptr, cnt_merch, 128, Wl + 3 * 16384,
             h_merch, Wr + 3 * 16384, 128, bl + 3 * 128,
             nullptr, nullptr, nullptr, nullptr, 1, nullptr, nullptr, h_merch, N_MERCH);

        // tx update: relu(h_tx @ (Wr0+Wr2) + bl0+bl2 + p_card[e_card[t]] + p_merch[e_merch[t]])
        // (relies on e_tx_c / e_tx_m == arange: each tx has exactly one edge of each type)
        gemm(h_tx, nullptr, nullptr, 128, Wsum, nullptr, nullptr, 0, bsum,
             p_card, e_card, p_merch, e_merch, 1, nullptr, nullptr, h_tx, N_TX);
    }

    // head: logits = relu(h_tx @ h1_W + h1_b) @ h2_W + h2_b
    gemm(h_tx, nullptr, nullptr, 128, h1_W, nullptr, nullptr, 0, h1_b,
         nullptr, nullptr, nullptr, nullptr, 1, h2_W, h2_b, (float*)d_out, N_TX);
}

// Round 2
// 1084.098 us; speedup vs baseline: 2.0348x; 2.0348x over previous
//
#include <hip/hip_runtime.h>

// HeteroSAGE on MI355X — round 2: replace atomic scatter-mean with
// CSR-build (once per launch) + per-wave gather-mean.
// R1 post-mortem: scatter_agg was 2x692us = 63% of runtime, 51.2M scalar fp32
// atomics/dispatch, WRITE_SIZE 812MB (atomic write-through), VALUBusy 0.8%.

#define N_TX    200000
#define N_CARD  50000
#define N_MERCH 10000
#define NE      200000
#define TM 64
#define KC 32

// ---------------- unified fp32 GEMM (unchanged from R1, minus cnt path) ----
// OUT[M,128] = act( A1[rowIdx1] @ W1 (+ A2 @ W2) + bias + P1[I1[r]] + P2[I2[r]] )
// optional head: out[r] = relu(row) . h2W + h2b
__global__ __launch_bounds__(256) void fused_gemm(
    const float* __restrict__ A1, const int* __restrict__ rowIdx1, int K1,
    const float* __restrict__ W1,
    const float* __restrict__ A2, const float* __restrict__ W2, int K2,
    const float* __restrict__ bias,
    const float* __restrict__ P1, const int* __restrict__ I1,
    const float* __restrict__ P2, const int* __restrict__ I2,
    int do_relu,
    const float* __restrict__ h2W, const float* __restrict__ h2b,
    float* __restrict__ OUT,
    int M)
{
    __shared__ float At[KC][TM + 4];
    __shared__ float Wt[KC][128];
    const int tid = threadIdx.x;
    const int tc = tid & 31;
    const int tr = tid >> 5;
    const int base = blockIdx.x * TM;

    float acc[8][4];
#pragma unroll
    for (int i = 0; i < 8; ++i)
#pragma unroll
        for (int j = 0; j < 4; ++j) acc[i][j] = 0.f;

    for (int pair = 0; pair < 2; ++pair) {
        const float* A = (pair == 0) ? A1 : A2;
        if (!A) continue;
        const float* W = (pair == 0) ? W1 : W2;
        const int K = (pair == 0) ? K1 : K2;
        const int* rIdx = (pair == 0) ? rowIdx1 : nullptr;
        const int nkc = K >> 5;
        for (int kc = 0; kc < nkc; ++kc) {
            const int k0 = kc << 5;
            __syncthreads();
#pragma unroll
            for (int t = 0; t < 2; ++t) {
                int u = tid * 2 + t;
                int r = u >> 3;
                int q = u & 7;
                int gr = base + r;
                float4 v = make_float4(0.f, 0.f, 0.f, 0.f);
                if (gr < M) {
                    int ar = rIdx ? rIdx[gr] : gr;
                    v = *reinterpret_cast<const float4*>(A + (size_t)ar * K + k0 + q * 4);
                }
                At[q * 4 + 0][r] = v.x; At[q * 4 + 1][r] = v.y;
                At[q * 4 + 2][r] = v.z; At[q * 4 + 3][r] = v.w;
            }
#pragma unroll
            for (int t = 0; t < 4; ++t) {
                int u = tid + t * 256;
                int k = u >> 5;
                int c4 = u & 31;
                *reinterpret_cast<float4*>(&Wt[k][c4 * 4]) =
                    *reinterpret_cast<const float4*>(W + (size_t)(k0 + k) * 128 + c4 * 4);
            }
            __syncthreads();
#pragma unroll
            for (int k = 0; k < KC; ++k) {
                float4 bq = *reinterpret_cast<const float4*>(&Wt[k][tc * 4]);
                float4 a0 = *reinterpret_cast<const float4*>(&At[k][tr * 8]);
                float4 a1 = *reinterpret_cast<const float4*>(&At[k][tr * 8 + 4]);
                float av[8] = {a0.x, a0.y, a0.z, a0.w, a1.x, a1.y, a1.z, a1.w};
                float bv[4] = {bq.x, bq.y, bq.z, bq.w};
#pragma unroll
                for (int i = 0; i < 8; ++i)
#pragma unroll
                    for (int j = 0; j < 4; ++j)
                        acc[i][j] = fmaf(av[i], bv[j], acc[i][j]);
            }
        }
    }

    float4 bi = make_float4(0.f, 0.f, 0.f, 0.f);
    if (bias) bi = *reinterpret_cast<const float4*>(bias + tc * 4);
    float4 h2v = make_float4(0.f, 0.f, 0.f, 0.f);
    if (h2W) h2v = *reinterpret_cast<const float4*>(h2W + tc * 4);

#pragma unroll
    for (int i = 0; i < 8; ++i) {
        int gr = base + tr * 8 + i;
        bool valid = gr < M;
        int grc = valid ? gr : 0;
        float4 o;
        o.x = acc[i][0] + bi.x; o.y = acc[i][1] + bi.y;
        o.z = acc[i][2] + bi.z; o.w = acc[i][3] + bi.w;
        if (P1) {
            int ix = I1 ? I1[grc] : grc;
            float4 p = *reinterpret_cast<const float4*>(P1 + (size_t)ix * 128 + tc * 4);
            o.x += p.x; o.y += p.y; o.z += p.z; o.w += p.w;
        }
        if (P2) {
            int ix = I2 ? I2[grc] : grc;
            float4 p = *reinterpret_cast<const float4*>(P2 + (size_t)ix * 128 + tc * 4);
            o.x += p.x; o.y += p.y; o.z += p.z; o.w += p.w;
        }
        if (do_relu) {
            o.x = fmaxf(o.x, 0.f); o.y = fmaxf(o.y, 0.f);
            o.z = fmaxf(o.z, 0.f); o.w = fmaxf(o.w, 0.f);
        }
        if (h2W) {
            float s = o.x * h2v.x + o.y * h2v.y + o.z * h2v.z + o.w * h2v.w;
            s += __shfl_xor(s, 1);  s += __shfl_xor(s, 2);
            s += __shfl_xor(s, 4);  s += __shfl_xor(s, 8);
            s += __shfl_xor(s, 16);
            if (tc == 0 && valid) OUT[gr] = s + h2b[0];
        } else if (valid) {
            *reinterpret_cast<float4*>(OUT + (size_t)gr * 128 + tc * 4) = o;
        }
    }
}

// ---------------- CSR build (once per launch; edges constant in-call) ------

// histogram of both dst index arrays
__global__ __launch_bounds__(256) void hist_kernel(
    const int* __restrict__ e_card, const int* __restrict__ e_merch,
    int* __restrict__ hist_c, int* __restrict__ hist_m, int E)
{
    int i = blockIdx.x * 256 + threadIdx.x;
    if (i < E) {
        atomicAdd(&hist_c[e_card[i]], 1);
        atomicAdd(&hist_m[e_merch[i]], 1);
    }
}

// single-block exclusive scan: offs[0..n] from hist[0..n-1]; cursor := offs
__global__ __launch_bounds__(1024) void scan_kernel(
    const int* __restrict__ hist, int* __restrict__ offs,
    int* __restrict__ cursor, int n)
{
    __shared__ int wsum[16];
    __shared__ int s_carry;
    const int tid = threadIdx.x, lane = tid & 63, wid = tid >> 6;
    if (tid == 0) s_carry = 0;
    __syncthreads();
    for (int base = 0; base < n; base += 1024) {
        int i = base + tid;
        int v = (i < n) ? hist[i] : 0;
        int x = v;
#pragma unroll
        for (int d = 1; d < 64; d <<= 1) {
            int t = __shfl_up(x, d);
            if (lane >= d) x += t;
        }
        if (lane == 63) wsum[wid] = x;
        __syncthreads();
        if (wid == 0) {
            int y = (lane < 16) ? wsum[lane] : 0;
#pragma unroll
            for (int d = 1; d < 16; d <<= 1) {
                int t = __shfl_up(y, d);
                if (lane >= d) y += t;
            }
            if (lane < 16) wsum[lane] = y;   // inclusive scan of wave sums
        }
        __syncthreads();
        int wbase = (wid > 0) ? wsum[wid - 1] : 0;
        int excl = s_carry + wbase + x - v;
        if (i < n) { offs[i] = excl; cursor[i] = excl; }
        __syncthreads();
        if (tid == 0) s_carry += wsum[15];
        __syncthreads();
    }
    if (threadIdx.x == 0) offs[n] = s_carry;
}

// place src (tx) indices into CSR buckets (order within bucket arbitrary)
__global__ __launch_bounds__(256) void place_kernel(
    const int* __restrict__ e_card, const int* __restrict__ e_tx_c,
    const int* __restrict__ e_merch, const int* __restrict__ e_tx_m,
    int* __restrict__ cur_c, int* __restrict__ eidx_c,
    int* __restrict__ cur_m, int* __restrict__ eidx_m, int E)
{
    int i = blockIdx.x * 256 + threadIdx.x;
    if (i < E) {
        int pc = atomicAdd(&cur_c[e_card[i]], 1);
        eidx_c[pc] = e_tx_c[i];
        int pm = atomicAdd(&cur_m[e_merch[i]], 1);
        eidx_m[pm] = e_tx_m[i];
    }
}

// one wave per dst node: mean of its gathered h_src rows (coalesced float2/lane)
__global__ __launch_bounds__(256) void gather_mean(
    const float* __restrict__ h_src, const int* __restrict__ offs,
    const int* __restrict__ eidx, float* __restrict__ out_mean, int n_dst)
{
    const int lane = threadIdx.x & 63;
    const int d = blockIdx.x * 4 + (threadIdx.x >> 6);
    if (d >= n_dst) return;
    const int s = offs[d], e = offs[d + 1];
    float2 acc = make_float2(0.f, 0.f);
    for (int p = s; p < e; ++p) {
        int tx = eidx[p];
        float2 v = *reinterpret_cast<const float2*>(h_src + (size_t)tx * 128 + lane * 2);
        acc.x += v.x; acc.y += v.y;
    }
    const float inv = (e > s) ? 1.0f / (float)(e - s) : 0.f;  // empty -> 0 (ref: agg=0)
    acc.x *= inv; acc.y *= inv;
    *reinterpret_cast<float2*>(out_mean + (size_t)d * 128 + lane * 2) = acc;
}

// Wsum = Wr0 + Wr2, bsum = bl0 + bl2
__global__ void wsum_kernel(const float* __restrict__ w0, const float* __restrict__ w2,
                            const float* __restrict__ b0, const float* __restrict__ b2,
                            float* __restrict__ Wsum, float* __restrict__ bsum)
{
    int i = blockIdx.x * 256 + threadIdx.x;
    if (i < 16384) Wsum[i] = w0[i] + w2[i];
    if (i < 128) bsum[i] = b0[i] + b2[i];
}

extern "C" void kernel_launch(void* const* d_in, const int* in_sizes, int n_in,
                              void* d_out, int out_size, void* d_ws, size_t ws_size,
                              hipStream_t stream)
{
    const float* tx_x        = (const float*)d_in[0];
    const int*   card_ids    = (const int*)d_in[1];
    const int*   merch_ids   = (const int*)d_in[2];
    const int*   e_card      = (const int*)d_in[3];
    const int*   e_tx_c      = (const int*)d_in[4];
    const int*   e_merch     = (const int*)d_in[5];
    const int*   e_tx_m      = (const int*)d_in[6];
    const float* card_emb    = (const float*)d_in[7];
    const float* merch_emb   = (const float*)d_in[8];
    const float* card_proj_W = (const float*)d_in[9];
    const float* card_proj_b = (const float*)d_in[10];
    const float* merch_proj_W= (const float*)d_in[11];
    const float* merch_proj_b= (const float*)d_in[12];
    const float* tx_W        = (const float*)d_in[13];
    const float* tx_b        = (const float*)d_in[14];
    const float* conv_Wl     = (const float*)d_in[15];
    const float* conv_bl     = (const float*)d_in[16];
    const float* conv_Wr     = (const float*)d_in[17];
    const float* h1_W        = (const float*)d_in[18];
    const float* h1_b        = (const float*)d_in[19];
    const float* h2_W        = (const float*)d_in[20];
    const float* h2_b        = (const float*)d_in[21];

    float* ws = (float*)d_ws;
    float* h_tx       = ws; ws += (size_t)N_TX * 128;
    float* h_card     = ws; ws += (size_t)N_CARD * 128;
    float* h_merch    = ws; ws += (size_t)N_MERCH * 128;
    float* p_card     = ws; ws += (size_t)N_CARD * 128;
    float* p_merch    = ws; ws += (size_t)N_MERCH * 128;
    float* mean_card  = ws; ws += (size_t)N_CARD * 128;
    float* mean_merch = ws; ws += (size_t)N_MERCH * 128;
    float* Wsum = ws; ws += 128 * 128;
    float* bsum = ws; ws += 128;
    int* iw = (int*)ws;
    int* hist_c = iw; iw += N_CARD;     // hist_c + hist_m contiguous: one memset
    int* hist_m = iw; iw += N_MERCH;
    int* offs_c = iw; iw += N_CARD + 1;
    int* cur_c  = iw; iw += N_CARD;
    int* eidx_c = iw; iw += NE;
    int* offs_m = iw; iw += N_MERCH + 1;
    int* cur_m  = iw; iw += N_MERCH;
    int* eidx_m = iw; iw += NE;

    auto gemm = [&](const float* A1, const int* ri, int K1,
                    const float* W1, const float* A2, const float* W2, int K2,
                    const float* bias, const float* P1, const int* I1,
                    const float* P2, const int* I2, int relu,
                    const float* h2w, const float* h2bb, float* out, int M) {
        fused_gemm<<<dim3((M + TM - 1) / TM), dim3(256), 0, stream>>>(
            A1, ri, K1, W1, A2, W2, K2, bias, P1, I1, P2, I2, relu,
            h2w, h2bb, out, M);
    };

    // ---- CSR build (edges fixed within this call; reused by both layers)
    hipMemsetAsync(hist_c, 0, (size_t)(N_CARD + N_MERCH) * 4, stream);
    hist_kernel<<<dim3((NE + 255) / 256), dim3(256), 0, stream>>>(
        e_card, e_merch, hist_c, hist_m, NE);
    scan_kernel<<<dim3(1), dim3(1024), 0, stream>>>(hist_c, offs_c, cur_c, N_CARD);
    scan_kernel<<<dim3(1), dim3(1024), 0, stream>>>(hist_m, offs_m, cur_m, N_MERCH);
    place_kernel<<<dim3((NE + 255) / 256), dim3(256), 0, stream>>>(
        e_card, e_tx_c, e_merch, e_tx_m, cur_c, eidx_c, cur_m, eidx_m, NE);

    // ---- input encoders
    gemm(tx_x, nullptr, 128, tx_W, nullptr, nullptr, 0, tx_b,
         nullptr, nullptr, nullptr, nullptr, 1, nullptr, nullptr, h_tx, N_TX);
    gemm(card_emb, card_ids, 64, card_proj_W, nullptr, nullptr, 0,
         card_proj_b, nullptr, nullptr, nullptr, nullptr, 0, nullptr, nullptr,
         h_card, N_CARD);
    gemm(merch_emb, merch_ids, 64, merch_proj_W, nullptr, nullptr, 0,
         merch_proj_b, nullptr, nullptr, nullptr, nullptr, 0, nullptr, nullptr,
         h_merch, N_MERCH);

    for (int l = 0; l < 2; ++l) {
        const float* Wl = conv_Wl + (size_t)l * 4 * 16384;
        const float* Wr = conv_Wr + (size_t)l * 4 * 16384;
        const float* bl = conv_bl + (size_t)l * 4 * 128;

        // gather-mean into mean_card / mean_merch (no atomics, no memset)
        gather_mean<<<dim3((N_CARD + 3) / 4), dim3(256), 0, stream>>>(
            h_tx, offs_c, eidx_c, mean_card, N_CARD);
        gather_mean<<<dim3((N_MERCH + 3) / 4), dim3(256), 0, stream>>>(
            h_tx, offs_m, eidx_m, mean_merch, N_MERCH);
        wsum_kernel<<<dim3(64), dim3(256), 0, stream>>>(
            Wr + 0 * 16384, Wr + 2 * 16384, bl + 0 * 128, bl + 2 * 128, Wsum, bsum);

        // p_* = h_* @ Wl[etype] (pre-update hidden) for the tx-side gather
        gemm(h_card, nullptr, 128, Wl + 0 * 16384, nullptr, nullptr, 0,
             nullptr, nullptr, nullptr, nullptr, nullptr, 0, nullptr, nullptr,
             p_card, N_CARD);
        gemm(h_merch, nullptr, 128, Wl + 2 * 16384, nullptr, nullptr, 0,
             nullptr, nullptr, nullptr, nullptr, nullptr, 0, nullptr, nullptr,
             p_merch, N_MERCH);

        // card/merch updates: relu(mean @ Wl + h @ Wr + bl), in-place (row-local)
        gemm(mean_card, nullptr, 128, Wl + 1 * 16384,
             h_card, Wr + 1 * 16384, 128, bl + 1 * 128,
             nullptr, nullptr, nullptr, nullptr, 1, nullptr, nullptr, h_card, N_CARD);
        gemm(mean_merch, nullptr, 128, Wl + 3 * 16384,
             h_merch, Wr + 3 * 16384, 128, bl + 3 * 128,
             nullptr, nullptr, nullptr, nullptr, 1, nullptr, nullptr, h_merch, N_MERCH);

        // tx update: relu(h_tx @ (Wr0+Wr2) + b0+b2 + p_card[e_card[t]] + p_merch[e_merch[t]])
        // (e_tx_c / e_tx_m == arange: each tx has exactly one edge of each type)
        gemm(h_tx, nullptr, 128, Wsum, nullptr, nullptr, 0, bsum,
             p_card, e_card, p_merch, e_merch, 1, nullptr, nullptr, h_tx, N_TX);
    }

    // head: logits = relu(h_tx @ h1_W + h1_b) @ h2_W + h2_b
    gemm(h_tx, nullptr, 128, h1_W, nullptr, nullptr, 0, h1_b,
         nullptr, nullptr, nullptr, nullptr, 1, h2_W, h2_b, (float*)d_out, N_TX);
}

// Round 3
// 812.648 us; speedup vs baseline: 2.7145x; 1.3340x over previous
//
#include <hip/hip_runtime.h>

// HeteroSAGE on MI355X — round 3: bf16 MFMA GEMMs (16x16x32, fp32 accum).
// R2 post-mortem: fp32 vector GEMM was the bottleneck (125us each, VALUBusy
// 47%, MfmaUtil 0, 52 TF of 157 TF vector peak). bf16 makes GEMMs memory-
// bound and uses the matrix pipe. h_* activations stored bf16; weights
// pre-transposed to [N][K] bf16 so A and B MFMA fragments are contiguous
// 16B loads. Threshold is bf16-floored (8 eps) so bf16 accuracy should hold.

#define N_TX    200000
#define N_CARD  50000
#define N_MERCH 10000
#define NE      200000

typedef __attribute__((ext_vector_type(8))) short short8;
typedef __attribute__((ext_vector_type(4))) float f32x4;

__device__ inline unsigned short f2b(float f) {
    unsigned u = __builtin_bit_cast(unsigned, f);
    unsigned r = (u + 0x7fffu + ((u >> 16) & 1u)) >> 16;   // RNE
    return (unsigned short)r;
}
__device__ inline float b2f(unsigned short s) {
    return __builtin_bit_cast(float, (unsigned)s << 16);
}

// ---------------------------------------------------------------------------
// Unified bf16 MFMA GEMM. OUT[M,128] = act( A1[rowIdx1] @ W1 (+ A2 @ W2)
//   + bias + P1[I1[r]] + P2[I2[r]] ); optional head: out[r]=relu(row).h2W+h2b
// WT* are bf16 weights pre-transposed to [N=128][K]. A1 may be fp32
// (a1_f32=1, converted inline) or bf16. A2 (if present) is bf16.
// Block: 128 rows x 128 cols; 4 waves; wave = 2 m-tiles x 8 n-tiles of 16x16.
__global__ __launch_bounds__(256, 2) void mfma_gemm(
    const void* __restrict__ A1, int a1_f32, const int* __restrict__ rowIdx1,
    int K1, const unsigned short* __restrict__ WT1,
    const void* __restrict__ A2, int K2, const unsigned short* __restrict__ WT2,
    const float* __restrict__ bias,
    const unsigned short* __restrict__ P1, const int* __restrict__ I1,
    const unsigned short* __restrict__ P2, const int* __restrict__ I2,
    int do_relu, const float* __restrict__ h2W, const float* __restrict__ h2b,
    void* __restrict__ OUT, int M)
{
    __shared__ unsigned short WTs[128 * 136];  // stride K+8 shorts, 16B aligned
    const int tid  = threadIdx.x;
    const int wave = tid >> 6;
    const int lane = tid & 63;
    const int quad = lane >> 4;
    const int l15  = lane & 15;
    const int base = blockIdx.x * 128;

    f32x4 acc[2][8];
#pragma unroll
    for (int mt = 0; mt < 2; ++mt)
#pragma unroll
        for (int nt = 0; nt < 8; ++nt)
            acc[mt][nt] = (f32x4){0.f, 0.f, 0.f, 0.f};

    for (int pass = 0; pass < 2; ++pass) {
        const void* A = (pass == 0) ? A1 : A2;
        if (!A) break;
        const int K = (pass == 0) ? K1 : K2;
        const unsigned short* WTg = (pass == 0) ? WT1 : WT2;
        const int* rIdx = (pass == 0) ? rowIdx1 : nullptr;
        const int a_f32 = (pass == 0) ? a1_f32 : 0;
        const int stride = K + 8;
        const int nkk = K >> 5;                  // 2 (K=64) or 4 (K=128)
        const int ksh = (K == 128) ? 7 : 6;

        __syncthreads();                          // protect prior-pass reads
        for (int i = tid * 8; i < (K << 7); i += 2048) {
            int row = i >> ksh;
            int off = i & (K - 1);
            *reinterpret_cast<short8*>(&WTs[row * stride + off]) =
                *reinterpret_cast<const short8*>(WTg + i);
        }
        __syncthreads();

        // A fragments (global, contiguous 16B per lane)
        short8 af[2][4];
#pragma unroll
        for (int mt = 0; mt < 2; ++mt) {
            int r = base + wave * 32 + mt * 16 + l15;
            int rc = (r < M) ? r : 0;
            int ar = rIdx ? rIdx[rc] : rc;
            if (a_f32) {
                const float* ap = (const float*)A + (size_t)ar * K + quad * 8;
#pragma unroll
                for (int kk = 0; kk < 4; ++kk) if (kk < nkk) {
                    float4 u = *reinterpret_cast<const float4*>(ap + kk * 32);
                    float4 v = *reinterpret_cast<const float4*>(ap + kk * 32 + 4);
                    short8 t;
                    t[0] = (short)f2b(u.x); t[1] = (short)f2b(u.y);
                    t[2] = (short)f2b(u.z); t[3] = (short)f2b(u.w);
                    t[4] = (short)f2b(v.x); t[5] = (short)f2b(v.y);
                    t[6] = (short)f2b(v.z); t[7] = (short)f2b(v.w);
                    af[mt][kk] = t;
                }
            } else {
                const unsigned short* ap =
                    (const unsigned short*)A + (size_t)ar * K + quad * 8;
#pragma unroll
                for (int kk = 0; kk < 4; ++kk) if (kk < nkk)
                    af[mt][kk] = *reinterpret_cast<const short8*>(ap + kk * 32);
            }
        }

        // MFMA over 8 n-tiles; B frags from LDS (2-way bank alias only)
#pragma unroll
        for (int nt = 0; nt < 8; ++nt) {
            short8 bf[4];
            const unsigned short* bp = &WTs[(nt * 16 + l15) * stride + quad * 8];
#pragma unroll
            for (int kk = 0; kk < 4; ++kk) if (kk < nkk)
                bf[kk] = *reinterpret_cast<const short8*>(bp + kk * 32);
#pragma unroll
            for (int mt = 0; mt < 2; ++mt)
#pragma unroll
                for (int kk = 0; kk < 4; ++kk) if (kk < nkk)
                    acc[mt][nt] = __builtin_amdgcn_mfma_f32_16x16x32_bf16(
                        af[mt][kk], bf[kk], acc[mt][nt], 0, 0, 0);
        }
    }

    // epilogue. C/D layout: col = l15 (+16*nt), row-in-tile = quad*4 + reg.
    float bias_v[8], h2wv[8];
#pragma unroll
    for (int nt = 0; nt < 8; ++nt) {
        int col = nt * 16 + l15;
        bias_v[nt] = bias ? bias[col] : 0.f;
        h2wv[nt]   = h2W  ? h2W[col]  : 0.f;
    }
    unsigned short* OUTb = (unsigned short*)OUT;
    float* OUTf = (float*)OUT;
#pragma unroll
    for (int mt = 0; mt < 2; ++mt) {
        int rbase = base + wave * 32 + mt * 16 + quad * 4;
#pragma unroll
        for (int reg = 0; reg < 4; ++reg) {
            int r = rbase + reg;
            bool valid = r < M;
            int rc = valid ? r : 0;
            size_t i1 = P1 ? (size_t)I1[rc] * 128 : 0;
            size_t i2 = P2 ? (size_t)I2[rc] * 128 : 0;
            float hsum = 0.f;
#pragma unroll
            for (int nt = 0; nt < 8; ++nt) {
                int col = nt * 16 + l15;
                float o = acc[mt][nt][reg] + bias_v[nt];
                if (P1) o += b2f(P1[i1 + col]);
                if (P2) o += b2f(P2[i2 + col]);
                if (do_relu) o = fmaxf(o, 0.f);
                if (h2W) hsum += o * h2wv[nt];
                else if (valid) OUTb[(size_t)r * 128 + col] = f2b(o);
            }
            if (h2W) {
                hsum += __shfl_xor(hsum, 1);
                hsum += __shfl_xor(hsum, 2);
                hsum += __shfl_xor(hsum, 4);
                hsum += __shfl_xor(hsum, 8);
                if (l15 == 0 && valid) OUTf[r] = hsum + h2b[0];
            }
        }
    }
}

// ---------------------------------------------------------------------------
// Weight prep: fp32 [K][128] -> bf16 transposed [128][K]; job 6/13 also does
// Wsum=Wr0+Wr2 and bsum=bl0+bl2. 18 jobs x 16384-short slots.
__global__ __launch_bounds__(256) void convert_weights(
    const float* __restrict__ tx_W, const float* __restrict__ card_proj_W,
    const float* __restrict__ merch_proj_W, const float* __restrict__ h1_W,
    const float* __restrict__ conv_Wl, const float* __restrict__ conv_Wr,
    const float* __restrict__ conv_bl,
    unsigned short* __restrict__ WT, float* __restrict__ bsum)
{
    int job = blockIdx.y;
    int K = 128;
    const float* src = nullptr;
    const float* src2 = nullptr;
    if (job == 0) src = tx_W;
    else if (job == 1) { src = card_proj_W; K = 64; }
    else if (job == 2) { src = merch_proj_W; K = 64; }
    else if (job == 3) src = h1_W;
    else {
        int l = (job - 4) / 7, e = (job - 4) % 7;
        const float* Wl = conv_Wl + (size_t)l * 4 * 16384;
        const float* Wr = conv_Wr + (size_t)l * 4 * 16384;
        switch (e) {
            case 0: src = Wl; break;
            case 1: src = Wl + 16384; break;
            case 2: src = Wl + 2 * 16384; break;
            case 3: src = Wl + 3 * 16384; break;
            case 4: src = Wr + 16384; break;
            case 5: src = Wr + 3 * 16384; break;
            default:
                src = Wr; src2 = Wr + 2 * 16384;
                if (blockIdx.x == 0 && threadIdx.x < 128) {
                    const float* bl = conv_bl + (size_t)l * 4 * 128;
                    bsum[l * 128 + threadIdx.x] =
                        bl[threadIdx.x] + bl[2 * 128 + threadIdx.x];
                }
                break;
        }
    }
    int e = blockIdx.x * 256 + threadIdx.x;
    if (e < (K << 7)) {
        int n = (K == 128) ? (e >> 7) : (e >> 6);
        int k = e & (K - 1);
        float v = src[(size_t)k * 128 + n];
        if (src2) v += src2[(size_t)k * 128 + n];
        WT[(size_t)job * 16384 + n * K + k] = f2b(v);
    }
}

// ---------------------------------------------------------------------------
// CSR build (edges fixed within call; reused across layers)
__global__ __launch_bounds__(256) void hist_kernel(
    const int* __restrict__ e_card, const int* __restrict__ e_merch,
    int* __restrict__ hist_c, int* __restrict__ hist_m, int E)
{
    int i = blockIdx.x * 256 + threadIdx.x;
    if (i < E) {
        atomicAdd(&hist_c[e_card[i]], 1);
        atomicAdd(&hist_m[e_merch[i]], 1);
    }
}

// 2 blocks: block 0 scans card hist, block 1 scans merch hist
__global__ __launch_bounds__(1024) void scan2_kernel(
    const int* __restrict__ hist_c, int* __restrict__ offs_c, int* __restrict__ cur_c, int nc,
    const int* __restrict__ hist_m, int* __restrict__ offs_m, int* __restrict__ cur_m, int nm)
{
    const int* hist = (blockIdx.x == 0) ? hist_c : hist_m;
    int* offs = (blockIdx.x == 0) ? offs_c : offs_m;
    int* cursor = (blockIdx.x == 0) ? cur_c : cur_m;
    int n = (blockIdx.x == 0) ? nc : nm;
    __shared__ int wsum[16];
    __shared__ int s_carry;
    const int tid = threadIdx.x, lane = tid & 63, wid = tid >> 6;
    if (tid == 0) s_carry = 0;
    __syncthreads();
    for (int base = 0; base < n; base += 1024) {
        int i = base + tid;
        int v = (i < n) ? hist[i] : 0;
        int x = v;
#pragma unroll
        for (int d = 1; d < 64; d <<= 1) {
            int t = __shfl_up(x, d);
            if (lane >= d) x += t;
        }
        if (lane == 63) wsum[wid] = x;
        __syncthreads();
        if (wid == 0) {
            int y = (lane < 16) ? wsum[lane] : 0;
#pragma unroll
            for (int d = 1; d < 16; d <<= 1) {
                int t = __shfl_up(y, d);
                if (lane >= d) y += t;
            }
            if (lane < 16) wsum[lane] = y;
        }
        __syncthreads();
        int wbase = (wid > 0) ? wsum[wid - 1] : 0;
        int excl = s_carry + wbase + x - v;
        if (i < n) { offs[i] = excl; cursor[i] = excl; }
        __syncthreads();
        if (tid == 0) s_carry += wsum[15];
        __syncthreads();
    }
    if (threadIdx.x == 0) offs[n] = s_carry;
}

__global__ __launch_bounds__(256) void place_kernel(
    const int* __restrict__ e_card, const int* __restrict__ e_tx_c,
    const int* __restrict__ e_merch, const int* __restrict__ e_tx_m,
    int* __restrict__ cur_c, int* __restrict__ eidx_c,
    int* __restrict__ cur_m, int* __restrict__ eidx_m, int E)
{
    int i = blockIdx.x * 256 + threadIdx.x;
    if (i < E) {
        int pc = atomicAdd(&cur_c[e_card[i]], 1);
        eidx_c[pc] = e_tx_c[i];
        int pm = atomicAdd(&cur_m[e_merch[i]], 1);
        eidx_m[pm] = e_tx_m[i];
    }
}

// one wave per dst node: mean of gathered bf16 h rows (4B/lane, coalesced)
__global__ __launch_bounds__(256) void gather_mean(
    const unsigned short* __restrict__ h_src, const int* __restrict__ offs,
    const int* __restrict__ eidx, unsigned short* __restrict__ out_mean, int n_dst)
{
    const int lane = threadIdx.x & 63;
    const int d = blockIdx.x * 4 + (threadIdx.x >> 6);
    if (d >= n_dst) return;
    const int s = offs[d], e = offs[d + 1];
    float a0 = 0.f, a1 = 0.f;
    for (int p = s; p < e; ++p) {
        int tx = eidx[p];
        unsigned v = *reinterpret_cast<const unsigned*>(
            h_src + (size_t)tx * 128 + lane * 2);
        a0 += b2f((unsigned short)(v & 0xffff));
        a1 += b2f((unsigned short)(v >> 16));
    }
    const float inv = (e > s) ? 1.0f / (float)(e - s) : 0.f;
    unsigned o = ((unsigned)f2b(a1 * inv) << 16) | f2b(a0 * inv);
    *reinterpret_cast<unsigned*>(out_mean + (size_t)d * 128 + lane * 2) = o;
}

// ---------------------------------------------------------------------------
extern "C" void kernel_launch(void* const* d_in, const int* in_sizes, int n_in,
                              void* d_out, int out_size, void* d_ws, size_t ws_size,
                              hipStream_t stream)
{
    const float* tx_x        = (const float*)d_in[0];
    const int*   card_ids    = (const int*)d_in[1];
    const int*   merch_ids   = (const int*)d_in[2];
    const int*   e_card      = (const int*)d_in[3];
    const int*   e_tx_c      = (const int*)d_in[4];
    const int*   e_merch     = (const int*)d_in[5];
    const int*   e_tx_m      = (const int*)d_in[6];
    const float* card_emb    = (const float*)d_in[7];
    const float* merch_emb   = (const float*)d_in[8];
    const float* card_proj_W = (const float*)d_in[9];
    const float* card_proj_b = (const float*)d_in[10];
    const float* merch_proj_W= (const float*)d_in[11];
    const float* merch_proj_b= (const float*)d_in[12];
    const float* tx_W        = (const float*)d_in[13];
    const float* tx_b        = (const float*)d_in[14];
    const float* conv_Wl     = (const float*)d_in[15];
    const float* conv_bl     = (const float*)d_in[16];
    const float* conv_Wr     = (const float*)d_in[17];
    const float* h1_W        = (const float*)d_in[18];
    const float* h1_b        = (const float*)d_in[19];
    const float* h2_W        = (const float*)d_in[20];
    const float* h2_b        = (const float*)d_in[21];

    char* wsb = (char*)d_ws;
    auto alloc = [&](size_t bytes) {
        char* p = wsb; wsb += (bytes + 255) & ~(size_t)255; return p;
    };
    unsigned short* h_tx       = (unsigned short*)alloc((size_t)N_TX * 128 * 2);
    unsigned short* h_card     = (unsigned short*)alloc((size_t)N_CARD * 128 * 2);
    unsigned short* h_merch    = (unsigned short*)alloc((size_t)N_MERCH * 128 * 2);
    unsigned short* p_card     = (unsigned short*)alloc((size_t)N_CARD * 128 * 2);
    unsigned short* p_merch    = (unsigned short*)alloc((size_t)N_MERCH * 128 * 2);
    unsigned short* mean_card  = (unsigned short*)alloc((size_t)N_CARD * 128 * 2);
    unsigned short* mean_merch = (unsigned short*)alloc((size_t)N_MERCH * 128 * 2);
    unsigned short* WT         = (unsigned short*)alloc((size_t)18 * 16384 * 2);
    float* bsum = (float*)alloc(2 * 128 * 4);
    int* hist_c = (int*)alloc((size_t)(N_CARD + N_MERCH) * 4);  // one memset
    int* hist_m = hist_c + N_CARD;
    int* offs_c = (int*)alloc((size_t)(N_CARD + 1) * 4);
    int* cur_c  = (int*)alloc((size_t)N_CARD * 4);
    int* eidx_c = (int*)alloc((size_t)NE * 4);
    int* offs_m = (int*)alloc((size_t)(N_MERCH + 1) * 4);
    int* cur_m  = (int*)alloc((size_t)N_MERCH * 4);
    int* eidx_m = (int*)alloc((size_t)NE * 4);

    auto WTj = [&](int job) { return WT + (size_t)job * 16384; };

    auto gemm = [&](const void* A1, int a1f32, const int* ri, int K1,
                    const unsigned short* W1, const void* A2, int K2,
                    const unsigned short* W2, const float* bias,
                    const unsigned short* P1, const int* I1,
                    const unsigned short* P2, const int* I2, int relu,
                    const float* h2w, const float* h2bb, void* out, int M) {
        mfma_gemm<<<dim3((M + 127) / 128), dim3(256), 0, stream>>>(
            A1, a1f32, ri, K1, W1, A2, K2, W2, bias, P1, I1, P2, I2, relu,
            h2w, h2bb, out, M);
    };

    // weight prep + CSR build
    convert_weights<<<dim3(64, 18), dim3(256), 0, stream>>>(
        tx_W, card_proj_W, merch_proj_W, h1_W, conv_Wl, conv_Wr, conv_bl,
        WT, bsum);
    hipMemsetAsync(hist_c, 0, (size_t)(N_CARD + N_MERCH) * 4, stream);
    hist_kernel<<<dim3((NE + 255) / 256), dim3(256), 0, stream>>>(
        e_card, e_merch, hist_c, hist_m, NE);
    scan2_kernel<<<dim3(2), dim3(1024), 0, stream>>>(
        hist_c, offs_c, cur_c, N_CARD, hist_m, offs_m, cur_m, N_MERCH);
    place_kernel<<<dim3((NE + 255) / 256), dim3(256), 0, stream>>>(
        e_card, e_tx_c, e_merch, e_tx_m, cur_c, eidx_c, cur_m, eidx_m, NE);

    // input encoders (fp32 A converted inline)
    gemm(tx_x, 1, nullptr, 128, WTj(0), nullptr, 0, nullptr, tx_b,
         nullptr, nullptr, nullptr, nullptr, 1, nullptr, nullptr, h_tx, N_TX);
    gemm(card_emb, 1, card_ids, 64, WTj(1), nullptr, 0, nullptr, card_proj_b,
         nullptr, nullptr, nullptr, nullptr, 0, nullptr, nullptr, h_card, N_CARD);
    gemm(merch_emb, 1, merch_ids, 64, WTj(2), nullptr, 0, nullptr, merch_proj_b,
         nullptr, nullptr, nullptr, nullptr, 0, nullptr, nullptr, h_merch, N_MERCH);

    for (int l = 0; l < 2; ++l) {
        const float* bl = conv_bl + (size_t)l * 4 * 128;
        int j = 4 + l * 7;   // Wl0,Wl1,Wl2,Wl3,Wr1,Wr3,Wsum

        gather_mean<<<dim3((N_CARD + 3) / 4), dim3(256), 0, stream>>>(
            h_tx, offs_c, eidx_c, mean_card, N_CARD);
        gather_mean<<<dim3((N_MERCH + 3) / 4), dim3(256), 0, stream>>>(
            h_tx, offs_m, eidx_m, mean_merch, N_MERCH);

        // p_* = h_* @ Wl[0/2] (pre-update hidden), for the tx-side gather
        gemm(h_card, 0, nullptr, 128, WTj(j + 0), nullptr, 0, nullptr, nullptr,
             nullptr, nullptr, nullptr, nullptr, 0, nullptr, nullptr, p_card, N_CARD);
        gemm(h_merch, 0, nullptr, 128, WTj(j + 2), nullptr, 0, nullptr, nullptr,
             nullptr, nullptr, nullptr, nullptr, 0, nullptr, nullptr, p_merch, N_MERCH);

        // card/merch updates: relu(mean@Wl + h@Wr + bl)  (in-place, row-local)
        gemm(mean_card, 0, nullptr, 128, WTj(j + 1), h_card, 128, WTj(j + 4),
             bl + 1 * 128, nullptr, nullptr, nullptr, nullptr, 1,
             nullptr, nullptr, h_card, N_CARD);
        gemm(mean_merch, 0, nullptr, 128, WTj(j + 3), h_merch, 128, WTj(j + 5),
             bl + 3 * 128, nullptr, nullptr, nullptr, nullptr, 1,
             nullptr, nullptr, h_merch, N_MERCH);

        // tx update: relu(h_tx@(Wr0+Wr2) + bl0+bl2 + p_card[e_card] + p_merch[e_merch])
        gemm(h_tx, 0, nullptr, 128, WTj(j + 6), nullptr, 0, nullptr,
             bsum + l * 128, p_card, e_card, p_merch, e_merch, 1,
             nullptr, nullptr, h_tx, N_TX);
    }

    // head: logits = relu(h_tx @ h1_W + h1_b) @ h2_W + h2_b  (fp32 out)
    gemm(h_tx, 0, nullptr, 128, WTj(3), nullptr, 0, nullptr, h1_b,
         nullptr, nullptr, nullptr, nullptr, 1, h2_W, h2_b, d_out, N_TX);
}